// Round 17
// baseline (195.266 us; speedup 1.0000x reference)
//
#include <hip/hip_runtime.h>
#include <math.h>

#define BB 2
#define NN 32768
#define KK 16
#define CC 64
#define MTOT (BB*NN*KK)   // 1048576

typedef short short8 __attribute__((ext_vector_type(8)));
typedef float f32x4 __attribute__((ext_vector_type(4)));

static_assert(MTOT == 1048576, "size");

__device__ __forceinline__ float frsq(float x) { return __builtin_amdgcn_rsqf(x); }

__device__ __forceinline__ unsigned cvtpk(float lo, float hi) {
    unsigned r;
    asm("v_cvt_pk_bf16_f32 %0, %1, %2" : "=v"(r) : "v"(lo), "v"(hi));
    return r;
}

__device__ __forceinline__ short f2bf(float f) {
    union { float f; unsigned u; } c; c.f = f;
    const unsigned r = c.u + 0x7FFFu + ((c.u >> 16) & 1u);   // RNE
    return (short)(r >> 16);
}

__device__ __forceinline__ float bf2f(unsigned short u) {
    union { unsigned u; float f; } c; c.u = ((unsigned)u) << 16; return c.f;
}

// agent-scope load: safe against stale per-XCD L2/L1 for cross-dispatch RAW
__device__ __forceinline__ float ld_dev(const float* p) {
    return __hip_atomic_load(p, __ATOMIC_RELAXED, __HIP_MEMORY_SCOPE_AGENT);
}

__device__ __forceinline__ f32x4 mfma16(short8 a, short8 b, f32x4 c) {
    return __builtin_amdgcn_mfma_f32_16x16x32_bf16(a, b, c, 0, 0, 0);
}

// pstats layout: 8 copies x 64 floats (copy p at pstats + p*64), j-semantics:
//   j 0..15  = stats0 (sum, sumsq)   j 16..31 = stats1   j 32..63 = stats2
#define PSTRIDE 64

template<int NJ>
__device__ __forceinline__ void sum_partials(const float* __restrict__ pst,
                                             float* S) {
#pragma unroll
    for (int j = 0; j < NJ; ++j) {
        float s = 0.f;
#pragma unroll
        for (int p = 0; p < 8; ++p) s += ld_dev(pst + p*PSTRIDE + j);
        S[j] = s;
    }
}

// ---------------------------------------------------------------------------
// geometry with preloaded center (cx..nmz) and neighbor index nj
// ---------------------------------------------------------------------------
__device__ __forceinline__ void geom12c(int b, int nj,
                                        float cx, float cy, float cz,
                                        float nmx, float nmy, float nmz,
                                        const float* __restrict__ xyz,
                                        const float* __restrict__ xyzn,
                                        float* win) {
    const size_t gj = (size_t)(b * NN + nj);
    const float gx = xyz[gj*3],  gy = xyz[gj*3+1],  gz = xyz[gj*3+2];
    const float gnx = xyzn[gj*3], gny = xyzn[gj*3+1], gnz = xyzn[gj*3+2];

    const float rx = gx - cx, ry = gy - cy, rz = gz - cz;
    const float ss = rx*rx + ry*ry + rz*rz;
    const float rinv = frsq(fmaxf(ss, 1e-24f));
    const float rlen = ss * rinv;
    const float rhx = rx*rinv, rhy = ry*rinv, rhz = rz*rinv;

    const float d_nr = nmx*rhx + nmy*rhy + nmz*rhz;
    float vx = nmx - d_nr*rhx, vy = nmy - d_nr*rhy, vz = nmz - d_nr*rhz;
    const float vinv = frsq(fmaxf(vx*vx + vy*vy + vz*vz, 1e-24f));
    vx *= vinv; vy *= vinv; vz *= vinv;

    float wx = rhy*vz - rhz*vy;
    float wy = rhz*vx - rhx*vz;
    float wz = rhx*vy - rhy*vx;
    const float winv = frsq(fmaxf(wx*wx + wy*wy + wz*wz, 1e-24f));
    wx *= winv; wy *= winv; wz *= winv;

    const float th1 = gnx*nmx + gny*nmy + gnz*nmz;
    const float th3 = rhx*gnx + rhy*gny + rhz*gnz;
    const float th4 = rx*nmx + ry*nmy + rz*nmz;
    const float th6 = gnx*vx + gny*vy + gnz*vz;
    const float th7 = gnx*wx + gny*wy + gnz*wz;
    const float ccx = gny*nmz - gnz*nmy;
    const float ccy = gnz*nmx - gnx*nmz;
    const float ccz = gnx*nmy - gny*nmx;
    const float th8 = rx*ccx + ry*ccy + rz*ccz;

    win[0]=th1; win[1]=d_nr; win[2]=th3; win[3]=th4; win[4]=th3; win[5]=th6;
    win[6]=th7; win[7]=th8; win[8]=rlen; win[9]=rx; win[10]=ry; win[11]=rz;
}

template<int ON, int IN>
__device__ __forceinline__ void lin(const float* a, const float* __restrict__ W,
                                    const float* __restrict__ bias, float* z) {
#pragma unroll
    for (int o = 0; o < ON; ++o) {
        float acc = bias[o];
#pragma unroll
        for (int c = 0; c < IN; ++c) acc += a[c] * W[o*IN + c];
        z[o] = acc;
    }
}

template<int NV>
__device__ __forceinline__ void block_reduce_atomic(const float* v, float* gdst) {
    __shared__ float red[NV * 4];
    const int lane = threadIdx.x & 63;
    const int wv   = threadIdx.x >> 6;
    float tmp[NV];
#pragma unroll
    for (int i = 0; i < NV; ++i) {
        float x = v[i];
#pragma unroll
        for (int off = 32; off > 0; off >>= 1) x += __shfl_down(x, off, 64);
        tmp[i] = x;
    }
    if (lane == 0) {
#pragma unroll
        for (int i = 0; i < NV; ++i) red[wv * NV + i] = tmp[i];
    }
    __syncthreads();
    if (threadIdx.x < NV) {
        float s = red[threadIdx.x] + red[NV + threadIdx.x] +
                  red[2*NV + threadIdx.x] + red[3*NV + threadIdx.x];
        __threadfence();   // release partial before device-scope atomic
        atomicAdd(gdst + threadIdx.x, s);
    }
    __syncthreads();
}

// ---------------------------------------------------------------------------
// kA: prep (weight frags + featsbf) + geometry -> z0 bf16 + rm4 + stats0
// Each thread: 4 CONSECUTIVE samples (share one center point; int4 nei load).
// ---------------------------------------------------------------------------
__global__ __launch_bounds__(256)
void kA(const float* __restrict__ xyz, const float* __restrict__ xyzn,
        const int* __restrict__ nei, const float* __restrict__ W0,
        const float* __restrict__ b0,
        const float* __restrict__ Wm1, const float* __restrict__ Wm2,
        const float* __restrict__ Wlin, const float* __restrict__ feats,
        unsigned short* __restrict__ z0ws, unsigned short* __restrict__ rmws,
        short* __restrict__ fWm1, short* __restrict__ fWm2,
        short* __restrict__ fWlin, unsigned short* __restrict__ featsbf,
        float* __restrict__ pstats) {
    const int t = threadIdx.x;
    const int gid  = blockIdx.x * 256 + t;
    const int gstr = gridDim.x * 256;

    for (int i = gid; i < 3072; i += gstr) {          // Wm1^T [96pad x 32]
        const int j = i & 7, l = (i >> 3) & 63, fn = i >> 9;
        const int ks = fn >> 1, nt = fn & 1;
        const int k = ks*32 + ((l >> 4) * 8) + j, n = nt*16 + (l & 15);
        fWm1[i] = (k < 67) ? f2bf(Wm1[n*67 + k]) : (short)0;
    }
    for (int i = gid; i < 1024; i += gstr) {          // Wm2^T [32 x 32]
        const int j = i & 7, l = (i >> 3) & 63, nt = i >> 9;
        const int k = ((l >> 4) * 8) + j, n = nt*16 + (l & 15);
        fWm2[i] = f2bf(Wm2[n*32 + k]);
    }
    for (int i = gid; i < 32768; i += gstr) {         // Wlin^T [512 x 64]
        const int j = i & 7, l = (i >> 3) & 63, fn = i >> 9;
        const int ks = fn >> 2, nt = fn & 3;
        const int k = ks*32 + ((l >> 4) * 8) + j, n = nt*16 + (l & 15);
        fWlin[i] = f2bf(Wlin[n*512 + k]);
    }
    for (int i = gid; i < (BB*NN*CC)/4; i += gstr) {  // feats -> bf16
        const float4 f = *(const float4*)(feats + (size_t)i*4);
        uint2 p; p.x = cvtpk(f.x, f.y); p.y = cvtpk(f.z, f.w);
        *(uint2*)(featsbf + (size_t)i*4) = p;
    }

    // ---- geometry: 4 consecutive samples, shared center ----
    const int s0 = gid * 4;
    const int pn = s0 >> 4;
    const int b  = pn >> 15;
    const int4 nj4 = *(const int4*)(nei + s0);
    const float cx  = xyz [(size_t)pn*3], cy  = xyz [(size_t)pn*3+1], cz  = xyz [(size_t)pn*3+2];
    const float nmx = xyzn[(size_t)pn*3], nmy = xyzn[(size_t)pn*3+1], nmz = xyzn[(size_t)pn*3+2];
    const int njs[4] = {nj4.x, nj4.y, nj4.z, nj4.w};

    float acc[16];
#pragma unroll
    for (int i = 0; i < 16; ++i) acc[i] = 0.f;
#pragma unroll
    for (int i = 0; i < 4; ++i) {
        const int s = s0 + i;
        float win[12];
        geom12c(b, njs[i], cx, cy, cz, nmx, nmy, nmz, xyz, xyzn, win);
        float z0[8];  lin<8,12>(win, W0, b0, z0);
        uint4 zp;
        zp.x = cvtpk(z0[0], z0[1]); zp.y = cvtpk(z0[2], z0[3]);
        zp.z = cvtpk(z0[4], z0[5]); zp.w = cvtpk(z0[6], z0[7]);
        *(uint4*)(z0ws + (size_t)s*8) = zp;
        uint2 rp; rp.x = cvtpk(win[9], win[10]); rp.y = cvtpk(win[11], 0.0f);
        *(uint2*)(rmws + (size_t)s*4) = rp;
#pragma unroll
        for (int o = 0; o < 8; ++o) { acc[o] += z0[o]; acc[8+o] += z0[o]*z0[o]; }
    }
    block_reduce_atomic<16>(acc, pstats + (blockIdx.x & 7) * PSTRIDE);
}

// ---------------------------------------------------------------------------
// kB: z0 -> a0 (hoisted BN coefs from summed partials) -> z1; stats1
// ---------------------------------------------------------------------------
__global__ __launch_bounds__(256)
void kB(const unsigned short* __restrict__ z0ws, const float* __restrict__ W1,
        const float* __restrict__ b1, const float* __restrict__ g0,
        const float* __restrict__ be0, float* __restrict__ pstats) {
    const int t = threadIdx.x;
    const float invM = 1.0f / (float)MTOT;
    float S[16]; sum_partials<16>(pstats, S);
    float sc0[8], sh0[8];
#pragma unroll
    for (int c = 0; c < 8; ++c) {
        const float m = S[c] * invM;
        const float v = S[8 + c] * invM - m*m;
        const float s = frsq(v + 1e-5f) * g0[c];
        sc0[c] = s; sh0[c] = be0[c] - m*s;
    }
    float acc[16];
#pragma unroll
    for (int i = 0; i < 16; ++i) acc[i] = 0.f;
#pragma unroll
    for (int i = 0; i < 4; ++i) {
        const int s = blockIdx.x*1024 + i*256 + t;
        const uint4 zz = *(const uint4*)(z0ws + (size_t)s*8);
        const unsigned short* q = (const unsigned short*)&zz;
        float a0[8];
#pragma unroll
        for (int c = 0; c < 8; ++c) a0[c] = fmaxf(bf2f(q[c])*sc0[c] + sh0[c], 0.f);
        float z1[8]; lin<8,8>(a0, W1, b1, z1);
#pragma unroll
        for (int o = 0; o < 8; ++o) { acc[o] += z1[o]; acc[8+o] += z1[o]*z1[o]; }
    }
    block_reduce_atomic<16>(acc, pstats + (blockIdx.x & 7) * PSTRIDE + 16);
}

// ---------------------------------------------------------------------------
// kC: z0 -> a0 -> z1 -> a1 -> z2; stats2
// ---------------------------------------------------------------------------
__global__ __launch_bounds__(256)
void kC(const unsigned short* __restrict__ z0ws, const float* __restrict__ W1,
        const float* __restrict__ b1, const float* __restrict__ W2,
        const float* __restrict__ b2, const float* __restrict__ g0,
        const float* __restrict__ be0, const float* __restrict__ g1,
        const float* __restrict__ be1, float* __restrict__ pstats) {
    const int t = threadIdx.x;
    const float invM = 1.0f / (float)MTOT;
    float S[32]; sum_partials<32>(pstats, S);
    float sc0[8], sh0[8], sc1[8], sh1[8];
#pragma unroll
    for (int c = 0; c < 8; ++c) {
        float m = S[c] * invM;
        float v = S[8 + c] * invM - m*m;
        float s = frsq(v + 1e-5f) * g0[c];
        sc0[c] = s; sh0[c] = be0[c] - m*s;
        m = S[16 + c] * invM;
        v = S[24 + c] * invM - m*m;
        s = frsq(v + 1e-5f) * g1[c];
        sc1[c] = s; sh1[c] = be1[c] - m*s;
    }
    float acc[32];
#pragma unroll
    for (int i = 0; i < 32; ++i) acc[i] = 0.f;
#pragma unroll
    for (int i = 0; i < 4; ++i) {
        const int s = blockIdx.x*1024 + i*256 + t;
        const uint4 zz = *(const uint4*)(z0ws + (size_t)s*8);
        const unsigned short* q = (const unsigned short*)&zz;
        float a0[8];
#pragma unroll
        for (int c = 0; c < 8; ++c) a0[c] = fmaxf(bf2f(q[c])*sc0[c] + sh0[c], 0.f);
        float z1[8]; lin<8,8>(a0, W1, b1, z1);
        float a1[8];
#pragma unroll
        for (int c = 0; c < 8; ++c) a1[c] = fmaxf(z1[c]*sc1[c] + sh1[c], 0.f);
        float z2[16]; lin<16,8>(a1, W2, b2, z2);
#pragma unroll
        for (int o = 0; o < 16; ++o) { acc[o] += z2[o]; acc[16+o] += z2[o]*z2[o]; }
    }
    block_reduce_atomic<32>(acc, pstats + (blockIdx.x & 7) * PSTRIDE + 32);
}

// ---------------------------------------------------------------------------
// k_fin: sum partials (agent-scope loads) -> fold coefficients (1 block)
// fold: [0..7]=sc0 [8..15]=sh0 [16..79]=W1f [80..87]=b1f [88..215]=W2f [216..231]=b2f
// ---------------------------------------------------------------------------
__global__ void k_fin(const float* __restrict__ pstats,
                      const float* __restrict__ g0, const float* __restrict__ be0,
                      const float* __restrict__ W1, const float* __restrict__ b1,
                      const float* __restrict__ g1, const float* __restrict__ be1,
                      const float* __restrict__ W2, const float* __restrict__ b2,
                      const float* __restrict__ g2, const float* __restrict__ be2,
                      float* __restrict__ fold) {
    __shared__ float S[64];
    __shared__ float sc[32], sh[32];
    const int t = threadIdx.x;
    const float invM = 1.0f / (float)MTOT;
    if (t < 64) {
        float s = 0.f;
#pragma unroll
        for (int p = 0; p < 8; ++p) s += ld_dev(pstats + p*PSTRIDE + t);
        S[t] = s;
    }
    __syncthreads();
    if (t < 8) {
        const float m = S[t]*invM, v = S[8+t]*invM - m*m;
        const float s = frsq(v + 1e-5f) * g0[t];
        sc[t] = s; sh[t] = be0[t] - m*s;
    } else if (t < 16) {
        const int c = t - 8;
        const float m = S[16+c]*invM, v = S[24+c]*invM - m*m;
        const float s = frsq(v + 1e-5f) * g1[c];
        sc[t] = s; sh[t] = be1[c] - m*s;
    } else if (t < 32) {
        const int c = t - 16;
        const float m = S[32+c]*invM, v = S[48+c]*invM - m*m;
        const float s = frsq(v + 1e-5f) * g2[c];
        sc[t] = s; sh[t] = be2[c] - m*s;
    }
    __syncthreads();
    if (t < 8)   { fold[t] = sc[t]; fold[8+t] = sh[t]; }
    if (t < 64)  fold[16 + t] = sc[8 + (t >> 3)] * W1[t];
    if (t < 8)   fold[80 + t] = sc[8 + t]*b1[t] + sh[8 + t];
    if (t < 128) fold[88 + t] = sc[16 + (t >> 3)] * W2[t];
    if (t < 16)  fold[216 + t] = sc[16 + t]*b2[t] + sh[16 + t];
}

// ---------------------------------------------------------------------------
// k_fused: R8/R14 verbatim (prefetch prologue + fold-P0 + MFMA P1-P4)
// LDS: h1buf [256][40bf16] @0 (20480) -> overlaid by aggL [16][520bf16]
//      h2T [32][264bf16] @20480 (16896);  wBT [16p][272bf16] @37376 (8704)
// ---------------------------------------------------------------------------
__global__ __launch_bounds__(256, 3)
void k_fused(const float* __restrict__ feats,
             const unsigned short* __restrict__ featsbf,
             const int* __restrict__ nei,
             const float* __restrict__ bm1, const float* __restrict__ bm2,
             const float* __restrict__ blin, const float* __restrict__ fold,
             const short* __restrict__ fWm1, const short* __restrict__ fWm2,
             const short* __restrict__ fWlin,
             const unsigned short* __restrict__ z0ws,
             const unsigned short* __restrict__ rmws,
             float* __restrict__ out) {
    __shared__ __align__(16) unsigned char smem[46080];
    const int t    = threadIdx.x;
    const int lane = t & 63;
    const int wv   = t >> 6;
    const int blk  = blockIdx.x;
    const int sbase = blk * 256;
    const int b     = (blk >= 2048) ? 1 : 0;
    const int lrow  = lane & 15;
    const int kq    = lane >> 4;

    // ---- prologue: issue ALL global loads up front ----
    int njv[4];
#pragma unroll
    for (int mt = 0; mt < 4; ++mt)
        njv[mt] = nei[sbase + wv*64 + mt*16 + lrow];

    const uint4 zz = *(const uint4*)(z0ws + (size_t)(sbase + t)*8);

    short8 bW1[3][2];
#pragma unroll
    for (int ks = 0; ks < 3; ++ks)
#pragma unroll
        for (int nt = 0; nt < 2; ++nt)
            bW1[ks][nt] = *(const short8*)(fWm1 + ((ks*2 + nt)*64 + lane)*8);
    short8 bW2[2];
    bW2[0] = *(const short8*)(fWm2 + (0*64 + lane)*8);
    bW2[1] = *(const short8*)(fWm2 + (1*64 + lane)*8);

    short8 fa[4][2];
    uint2  rmv[4];
#pragma unroll
    for (int mt = 0; mt < 4; ++mt) {
        const unsigned short* F = featsbf + ((size_t)(b*NN + njv[mt])) * CC;
        fa[mt][0] = *(const short8*)(F + kq*8);
        fa[mt][1] = *(const short8*)(F + 32 + kq*8);
        rmv[mt]   = *(const uint2*)(rmws + (size_t)(sbase + wv*64 + mt*16 + lrow)*4);
    }

    // ---- P0: z0 -> folded wn chain -> w -> wBT (hides load latency) ----
    {
        const unsigned short* q = (const unsigned short*)&zz;
        float a0[8];
#pragma unroll
        for (int c = 0; c < 8; ++c) a0[c] = fmaxf(bf2f(q[c])*fold[c] + fold[8+c], 0.f);
        float a1[8];
#pragma unroll
        for (int o = 0; o < 8; ++o) {
            float acc = fold[80 + o];
#pragma unroll
            for (int c = 0; c < 8; ++c) acc += a0[c] * fold[16 + o*8 + c];
            a1[o] = fmaxf(acc, 0.f);
        }
        const int p = t >> 4, kk = t & 15;
        unsigned short* WBT = (unsigned short*)(smem + 37376);
#pragma unroll
        for (int o = 0; o < 16; ++o) {
            float acc = fold[216 + o];
#pragma unroll
            for (int c = 0; c < 8; ++c) acc += a1[c] * fold[88 + o*8 + c];
            WBT[p*272 + o*16 + kk] = (unsigned short)f2bf(fmaxf(acc, 0.f));
        }
    }

    // ---- P1: h1 = relu([gfeat,rmiu] @ Wm1^T + bm1) ----
    {
        f32x4 C1[4][2];
#pragma unroll
        for (int mt = 0; mt < 4; ++mt)
#pragma unroll
            for (int nt = 0; nt < 2; ++nt)
                C1[mt][nt] = (f32x4){0.f, 0.f, 0.f, 0.f};

#pragma unroll
        for (int mt = 0; mt < 4; ++mt) {
            C1[mt][0] = mfma16(fa[mt][0], bW1[0][0], C1[mt][0]);
            C1[mt][1] = mfma16(fa[mt][0], bW1[0][1], C1[mt][1]);
            C1[mt][0] = mfma16(fa[mt][1], bW1[1][0], C1[mt][0]);
            C1[mt][1] = mfma16(fa[mt][1], bW1[1][1], C1[mt][1]);
            short8 ar = (short8){0,0,0,0,0,0,0,0};
            if (kq == 0)
                *(uint2*)&ar = rmv[mt];
            C1[mt][0] = mfma16(ar, bW1[2][0], C1[mt][0]);
            C1[mt][1] = mfma16(ar, bW1[2][1], C1[mt][1]);
        }
        unsigned short* H1 = (unsigned short*)smem;
#pragma unroll
        for (int mt = 0; mt < 4; ++mt)
#pragma unroll
            for (int nt = 0; nt < 2; ++nt) {
                const int c = nt*16 + lrow;
                const float bias = bm1[c];
#pragma unroll
                for (int reg = 0; reg < 4; ++reg) {
                    const int s = wv*64 + mt*16 + kq*4 + reg;
                    H1[s*40 + c] = (unsigned short)f2bf(fmaxf(C1[mt][nt][reg] + bias, 0.f));
                }
            }
    }

    // ---- P2: h2 = relu(h1 @ fWm2 + bm2) -> h2T ----
    {
        const unsigned short* H1 = (const unsigned short*)smem;
        f32x4 C2[4][2];
#pragma unroll
        for (int mt = 0; mt < 4; ++mt)
#pragma unroll
            for (int nt = 0; nt < 2; ++nt)
                C2[mt][nt] = (f32x4){0.f, 0.f, 0.f, 0.f};
#pragma unroll
        for (int mt = 0; mt < 4; ++mt) {
            const int s = wv*64 + mt*16 + lrow;
            const short8 a = *(const short8*)(H1 + s*40 + kq*8);
            C2[mt][0] = mfma16(a, bW2[0], C2[mt][0]);
            C2[mt][1] = mfma16(a, bW2[1], C2[mt][1]);
        }
        unsigned short* H2T = (unsigned short*)(smem + 20480);
#pragma unroll
        for (int mt = 0; mt < 4; ++mt)
#pragma unroll
            for (int nt = 0; nt < 2; ++nt) {
                const int c = nt*16 + lrow;
                const float bias = bm2[c];
                const int s0 = wv*64 + mt*16 + kq*4;
                const float r0 = fmaxf(C2[mt][nt][0] + bias, 0.f);
                const float r1 = fmaxf(C2[mt][nt][1] + bias, 0.f);
                const float r2 = fmaxf(C2[mt][nt][2] + bias, 0.f);
                const float r3 = fmaxf(C2[mt][nt][3] + bias, 0.f);
                uint2 pk; pk.x = cvtpk(r0, r1); pk.y = cvtpk(r2, r3);
                *(uint2*)&H2T[c*264 + s0] = pk;
            }
    }

    __syncthreads();   // h1buf reads done before aggL overlays region 0

    // ---- P3: agg[p] = h2_p^T @ w_p -> aggL [p][c*16+j] bf16 ----
    {
        const unsigned short* H2T = (const unsigned short*)(smem + 20480);
        const unsigned short* WBT = (const unsigned short*)(smem + 37376);
        unsigned short* AGG = (unsigned short*)smem;
#pragma unroll
        for (int pi = 0; pi < 4; ++pi) {
            const int p = wv*4 + pi;
            short8 bf = (short8){0,0,0,0,0,0,0,0};
            if (kq < 2)
                bf = *(const short8*)(WBT + p*272 + lrow*16 + kq*8);
#pragma unroll
            for (int ct = 0; ct < 2; ++ct) {
                short8 af = (short8){0,0,0,0,0,0,0,0};
                if (kq < 2) {
                    const int c = ct*16 + lrow;
                    af = *(const short8*)(H2T + c*264 + p*16 + kq*8);
                }
                f32x4 Cg = (f32x4){0.f, 0.f, 0.f, 0.f};
                Cg = mfma16(af, bf, Cg);
#pragma unroll
                for (int reg = 0; reg < 4; ++reg) {
                    const int c = ct*16 + kq*4 + reg;
                    AGG[p*520 + c*16 + lrow] = (unsigned short)f2bf(Cg[reg]);
                }
            }
        }
    }

    __syncthreads();   // aggL complete

    // ---- P4: out = relu(agg @ Wlin^T + blin) + feats ----
    {
        const unsigned short* AGG = (const unsigned short*)smem;
        const int nt = wv;
        f32x4 Co = (f32x4){0.f, 0.f, 0.f, 0.f};
#pragma unroll
        for (int ks = 0; ks < 16; ++ks) {
            const short8 a  = *(const short8*)(AGG + lrow*520 + ks*32 + kq*8);
            const short8 bf = *(const short8*)(fWlin + ((ks*4 + nt)*64 + lane)*8);
            Co = mfma16(a, bf, Co);
        }
        const int o = nt*16 + lrow;
        const float bias = blin[o];
#pragma unroll
        for (int reg = 0; reg < 4; ++reg) {
            const int p = kq*4 + reg;
            const size_t gp = (size_t)blk*16 + p;
            out[gp*CC + o] = fmaxf(Co[reg] + bias, 0.f) + feats[gp*CC + o];
        }
    }
}

// ---------------------------------------------------------------------------
extern "C" void kernel_launch(void* const* d_in, const int* in_sizes, int n_in,
                              void* d_out, int out_size, void* d_ws, size_t ws_size,
                              hipStream_t stream) {
    const float* xyz  = (const float*)d_in[0];
    const float* feats= (const float*)d_in[1];
    const float* xyzn = (const float*)d_in[2];
    const int*   nei  = (const int*)  d_in[3];
    const float* Wm1  = (const float*)d_in[4];
    const float* bm1  = (const float*)d_in[5];
    const float* Wm2  = (const float*)d_in[6];
    const float* bm2  = (const float*)d_in[7];
    const float* W0   = (const float*)d_in[8];
    const float* b0   = (const float*)d_in[9];
    const float* g0   = (const float*)d_in[10];
    const float* be0  = (const float*)d_in[11];
    const float* W1   = (const float*)d_in[12];
    const float* b1   = (const float*)d_in[13];
    const float* g1   = (const float*)d_in[14];
    const float* be1  = (const float*)d_in[15];
    const float* W2   = (const float*)d_in[16];
    const float* b2   = (const float*)d_in[17];
    const float* g2   = (const float*)d_in[18];
    const float* be2  = (const float*)d_in[19];
    const float* Wlin = (const float*)d_in[20];
    const float* blin = (const float*)d_in[21];

    float* out = (float*)d_out;
    char*  ws  = (char*)d_ws;

    float*          pstats  = (float*)ws;                        // 8x64 f = 2 KB
    float*          fold    = (float*)(ws + 8192);               // 232 f
    short*          fWm1    = (short*)(ws + 10240);              // 6144 B
    short*          fWm2    = (short*)(ws + 16384);              // 2048 B
    short*          fWlin   = (short*)(ws + 20480);              // 64 KB
    unsigned short* featsbf = (unsigned short*)(ws + 131072);    // 8 MB
    unsigned short* z0ws    = (unsigned short*)(ws + 8519680);   // 16 MB
    unsigned short* rmws    = (unsigned short*)(ws + 25296896);  // 8 MB

    hipMemsetAsync(pstats, 0, 8192, stream);

    kA<<<1024, 256, 0, stream>>>(xyz, xyzn, nei, W0, b0, Wm1, Wm2, Wlin,
                                 feats, z0ws, rmws, fWm1, fWm2, fWlin,
                                 featsbf, pstats);
    kB<<<1024, 256, 0, stream>>>(z0ws, W1, b1, g0, be0, pstats);
    kC<<<1024, 256, 0, stream>>>(z0ws, W1, b1, W2, b2, g0, be0, g1, be1,
                                 pstats);
    k_fin<<<1, 256, 0, stream>>>(pstats, g0, be0, W1, b1, g1, be1,
                                 W2, b2, g2, be2, fold);
    k_fused<<<4096, 256, 0, stream>>>(feats, featsbf, nei, bm1, bm2, blin,
                                      fold, fWm1, fWm2, fWlin, z0ws, rmws, out);
}

// Round 18
// 125.979 us; speedup vs baseline: 1.5500x; 1.5500x over previous
//
#include <hip/hip_runtime.h>
#include <math.h>

#define BB 2
#define NN 32768
#define KK 16
#define CC 64
#define MTOT (BB*NN*KK)   // 1048576

typedef short short8 __attribute__((ext_vector_type(8)));
typedef float f32x4 __attribute__((ext_vector_type(4)));

static_assert(MTOT == 1048576, "size");

__device__ __forceinline__ float frsq(float x) { return __builtin_amdgcn_rsqf(x); }

__device__ __forceinline__ unsigned cvtpk(float lo, float hi) {
    unsigned r;
    asm("v_cvt_pk_bf16_f32 %0, %1, %2" : "=v"(r) : "v"(lo), "v"(hi));
    return r;
}

__device__ __forceinline__ short f2bf(float f) {
    union { float f; unsigned u; } c; c.f = f;
    const unsigned r = c.u + 0x7FFFu + ((c.u >> 16) & 1u);   // RNE
    return (short)(r >> 16);
}

__device__ __forceinline__ float bf2f(unsigned short u) {
    union { unsigned u; float f; } c; c.u = ((unsigned)u) << 16; return c.f;
}

// agent-scope load: guards against stale per-XCD L2/L1 for cross-dispatch RAW
// (read-side hardening only — NO producer threadfence: a device-scope fence in
// kA would drain ~32 MB of pending ws writes per block and cost ~75 µs, R17.)
__device__ __forceinline__ float ld_dev(const float* p) {
    return __hip_atomic_load(p, __ATOMIC_RELAXED, __HIP_MEMORY_SCOPE_AGENT);
}

__device__ __forceinline__ f32x4 mfma16(short8 a, short8 b, f32x4 c) {
    return __builtin_amdgcn_mfma_f32_16x16x32_bf16(a, b, c, 0, 0, 0);
}

// pstats layout: 8 copies x 64 floats (copy p at pstats + p*64), j-semantics:
//   j 0..15  = stats0 (sum, sumsq)   j 16..31 = stats1   j 32..63 = stats2
#define PSTRIDE 64

template<int NJ>
__device__ __forceinline__ void sum_partials(const float* __restrict__ pst,
                                             float* S) {
#pragma unroll
    for (int j = 0; j < NJ; ++j) {
        float s = 0.f;
#pragma unroll
        for (int p = 0; p < 8; ++p) s += ld_dev(pst + p*PSTRIDE + j);
        S[j] = s;
    }
}

// ---------------------------------------------------------------------------
// geometry with preloaded center (cx..nmz) and neighbor index nj
// ---------------------------------------------------------------------------
__device__ __forceinline__ void geom12c(int b, int nj,
                                        float cx, float cy, float cz,
                                        float nmx, float nmy, float nmz,
                                        const float* __restrict__ xyz,
                                        const float* __restrict__ xyzn,
                                        float* win) {
    const size_t gj = (size_t)(b * NN + nj);
    const float gx = xyz[gj*3],  gy = xyz[gj*3+1],  gz = xyz[gj*3+2];
    const float gnx = xyzn[gj*3], gny = xyzn[gj*3+1], gnz = xyzn[gj*3+2];

    const float rx = gx - cx, ry = gy - cy, rz = gz - cz;
    const float ss = rx*rx + ry*ry + rz*rz;
    const float rinv = frsq(fmaxf(ss, 1e-24f));
    const float rlen = ss * rinv;
    const float rhx = rx*rinv, rhy = ry*rinv, rhz = rz*rinv;

    const float d_nr = nmx*rhx + nmy*rhy + nmz*rhz;
    float vx = nmx - d_nr*rhx, vy = nmy - d_nr*rhy, vz = nmz - d_nr*rhz;
    const float vinv = frsq(fmaxf(vx*vx + vy*vy + vz*vz, 1e-24f));
    vx *= vinv; vy *= vinv; vz *= vinv;

    float wx = rhy*vz - rhz*vy;
    float wy = rhz*vx - rhx*vz;
    float wz = rhx*vy - rhy*vx;
    const float winv = frsq(fmaxf(wx*wx + wy*wy + wz*wz, 1e-24f));
    wx *= winv; wy *= winv; wz *= winv;

    const float th1 = gnx*nmx + gny*nmy + gnz*nmz;
    const float th3 = rhx*gnx + rhy*gny + rhz*gnz;
    const float th4 = rx*nmx + ry*nmy + rz*nmz;
    const float th6 = gnx*vx + gny*vy + gnz*vz;
    const float th7 = gnx*wx + gny*wy + gnz*wz;
    const float ccx = gny*nmz - gnz*nmy;
    const float ccy = gnz*nmx - gnx*nmz;
    const float ccz = gnx*nmy - gny*nmx;
    const float th8 = rx*ccx + ry*ccy + rz*ccz;

    win[0]=th1; win[1]=d_nr; win[2]=th3; win[3]=th4; win[4]=th3; win[5]=th6;
    win[6]=th7; win[7]=th8; win[8]=rlen; win[9]=rx; win[10]=ry; win[11]=rz;
}

template<int ON, int IN>
__device__ __forceinline__ void lin(const float* a, const float* __restrict__ W,
                                    const float* __restrict__ bias, float* z) {
#pragma unroll
    for (int o = 0; o < ON; ++o) {
        float acc = bias[o];
#pragma unroll
        for (int c = 0; c < IN; ++c) acc += a[c] * W[o*IN + c];
        z[o] = acc;
    }
}

template<int NV>
__device__ __forceinline__ void block_reduce_atomic(const float* v, float* gdst) {
    __shared__ float red[NV * 4];
    const int lane = threadIdx.x & 63;
    const int wv   = threadIdx.x >> 6;
    float tmp[NV];
#pragma unroll
    for (int i = 0; i < NV; ++i) {
        float x = v[i];
#pragma unroll
        for (int off = 32; off > 0; off >>= 1) x += __shfl_down(x, off, 64);
        tmp[i] = x;
    }
    if (lane == 0) {
#pragma unroll
        for (int i = 0; i < NV; ++i) red[wv * NV + i] = tmp[i];
    }
    __syncthreads();
    if (threadIdx.x < NV) {
        float s = red[threadIdx.x] + red[NV + threadIdx.x] +
                  red[2*NV + threadIdx.x] + red[3*NV + threadIdx.x];
        atomicAdd(gdst + threadIdx.x, s);
    }
}

// ---------------------------------------------------------------------------
// kA: prep (weight frags + featsbf) + geometry -> z0 bf16 + rm4 + stats0
// Each thread: 4 CONSECUTIVE samples (share one center point; int4 nei load).
// ---------------------------------------------------------------------------
__global__ __launch_bounds__(256)
void kA(const float* __restrict__ xyz, const float* __restrict__ xyzn,
        const int* __restrict__ nei, const float* __restrict__ W0,
        const float* __restrict__ b0,
        const float* __restrict__ Wm1, const float* __restrict__ Wm2,
        const float* __restrict__ Wlin, const float* __restrict__ feats,
        unsigned short* __restrict__ z0ws, unsigned short* __restrict__ rmws,
        short* __restrict__ fWm1, short* __restrict__ fWm2,
        short* __restrict__ fWlin, unsigned short* __restrict__ featsbf,
        float* __restrict__ pstats) {
    const int t = threadIdx.x;
    const int gid  = blockIdx.x * 256 + t;
    const int gstr = gridDim.x * 256;

    for (int i = gid; i < 3072; i += gstr) {          // Wm1^T [96pad x 32]
        const int j = i & 7, l = (i >> 3) & 63, fn = i >> 9;
        const int ks = fn >> 1, nt = fn & 1;
        const int k = ks*32 + ((l >> 4) * 8) + j, n = nt*16 + (l & 15);
        fWm1[i] = (k < 67) ? f2bf(Wm1[n*67 + k]) : (short)0;
    }
    for (int i = gid; i < 1024; i += gstr) {          // Wm2^T [32 x 32]
        const int j = i & 7, l = (i >> 3) & 63, nt = i >> 9;
        const int k = ((l >> 4) * 8) + j, n = nt*16 + (l & 15);
        fWm2[i] = f2bf(Wm2[n*32 + k]);
    }
    for (int i = gid; i < 32768; i += gstr) {         // Wlin^T [512 x 64]
        const int j = i & 7, l = (i >> 3) & 63, fn = i >> 9;
        const int ks = fn >> 2, nt = fn & 3;
        const int k = ks*32 + ((l >> 4) * 8) + j, n = nt*16 + (l & 15);
        fWlin[i] = f2bf(Wlin[n*512 + k]);
    }
    for (int i = gid; i < (BB*NN*CC)/4; i += gstr) {  // feats -> bf16
        const float4 f = *(const float4*)(feats + (size_t)i*4);
        uint2 p; p.x = cvtpk(f.x, f.y); p.y = cvtpk(f.z, f.w);
        *(uint2*)(featsbf + (size_t)i*4) = p;
    }

    // ---- geometry: 4 consecutive samples, shared center ----
    const int s0 = gid * 4;
    const int pn = s0 >> 4;
    const int b  = pn >> 15;
    const int4 nj4 = *(const int4*)(nei + s0);
    const float cx  = xyz [(size_t)pn*3], cy  = xyz [(size_t)pn*3+1], cz  = xyz [(size_t)pn*3+2];
    const float nmx = xyzn[(size_t)pn*3], nmy = xyzn[(size_t)pn*3+1], nmz = xyzn[(size_t)pn*3+2];
    const int njs[4] = {nj4.x, nj4.y, nj4.z, nj4.w};

    float acc[16];
#pragma unroll
    for (int i = 0; i < 16; ++i) acc[i] = 0.f;
#pragma unroll
    for (int i = 0; i < 4; ++i) {
        const int s = s0 + i;
        float win[12];
        geom12c(b, njs[i], cx, cy, cz, nmx, nmy, nmz, xyz, xyzn, win);
        float z0[8];  lin<8,12>(win, W0, b0, z0);
        uint4 zp;
        zp.x = cvtpk(z0[0], z0[1]); zp.y = cvtpk(z0[2], z0[3]);
        zp.z = cvtpk(z0[4], z0[5]); zp.w = cvtpk(z0[6], z0[7]);
        *(uint4*)(z0ws + (size_t)s*8) = zp;
        uint2 rp; rp.x = cvtpk(win[9], win[10]); rp.y = cvtpk(win[11], 0.0f);
        *(uint2*)(rmws + (size_t)s*4) = rp;
#pragma unroll
        for (int o = 0; o < 8; ++o) { acc[o] += z0[o]; acc[8+o] += z0[o]*z0[o]; }
    }
    block_reduce_atomic<16>(acc, pstats + (blockIdx.x & 7) * PSTRIDE);
}

// ---------------------------------------------------------------------------
// kB: z0 -> a0 (hoisted BN coefs from summed partials) -> z1; stats1
// ---------------------------------------------------------------------------
__global__ __launch_bounds__(256)
void kB(const unsigned short* __restrict__ z0ws, const float* __restrict__ W1,
        const float* __restrict__ b1, const float* __restrict__ g0,
        const float* __restrict__ be0, float* __restrict__ pstats) {
    const int t = threadIdx.x;
    const float invM = 1.0f / (float)MTOT;
    float S[16]; sum_partials<16>(pstats, S);
    float sc0[8], sh0[8];
#pragma unroll
    for (int c = 0; c < 8; ++c) {
        const float m = S[c] * invM;
        const float v = S[8 + c] * invM - m*m;
        const float s = frsq(v + 1e-5f) * g0[c];
        sc0[c] = s; sh0[c] = be0[c] - m*s;
    }
    float acc[16];
#pragma unroll
    for (int i = 0; i < 16; ++i) acc[i] = 0.f;
#pragma unroll
    for (int i = 0; i < 4; ++i) {
        const int s = blockIdx.x*1024 + i*256 + t;
        const uint4 zz = *(const uint4*)(z0ws + (size_t)s*8);
        const unsigned short* q = (const unsigned short*)&zz;
        float a0[8];
#pragma unroll
        for (int c = 0; c < 8; ++c) a0[c] = fmaxf(bf2f(q[c])*sc0[c] + sh0[c], 0.f);
        float z1[8]; lin<8,8>(a0, W1, b1, z1);
#pragma unroll
        for (int o = 0; o < 8; ++o) { acc[o] += z1[o]; acc[8+o] += z1[o]*z1[o]; }
    }
    block_reduce_atomic<16>(acc, pstats + (blockIdx.x & 7) * PSTRIDE + 16);
}

// ---------------------------------------------------------------------------
// kC: z0 -> a0 -> z1 -> a1 -> z2; stats2
// ---------------------------------------------------------------------------
__global__ __launch_bounds__(256)
void kC(const unsigned short* __restrict__ z0ws, const float* __restrict__ W1,
        const float* __restrict__ b1, const float* __restrict__ W2,
        const float* __restrict__ b2, const float* __restrict__ g0,
        const float* __restrict__ be0, const float* __restrict__ g1,
        const float* __restrict__ be1, float* __restrict__ pstats) {
    const int t = threadIdx.x;
    const float invM = 1.0f / (float)MTOT;
    float S[32]; sum_partials<32>(pstats, S);
    float sc0[8], sh0[8], sc1[8], sh1[8];
#pragma unroll
    for (int c = 0; c < 8; ++c) {
        float m = S[c] * invM;
        float v = S[8 + c] * invM - m*m;
        float s = frsq(v + 1e-5f) * g0[c];
        sc0[c] = s; sh0[c] = be0[c] - m*s;
        m = S[16 + c] * invM;
        v = S[24 + c] * invM - m*m;
        s = frsq(v + 1e-5f) * g1[c];
        sc1[c] = s; sh1[c] = be1[c] - m*s;
    }
    float acc[32];
#pragma unroll
    for (int i = 0; i < 32; ++i) acc[i] = 0.f;
#pragma unroll
    for (int i = 0; i < 4; ++i) {
        const int s = blockIdx.x*1024 + i*256 + t;
        const uint4 zz = *(const uint4*)(z0ws + (size_t)s*8);
        const unsigned short* q = (const unsigned short*)&zz;
        float a0[8];
#pragma unroll
        for (int c = 0; c < 8; ++c) a0[c] = fmaxf(bf2f(q[c])*sc0[c] + sh0[c], 0.f);
        float z1[8]; lin<8,8>(a0, W1, b1, z1);
        float a1[8];
#pragma unroll
        for (int c = 0; c < 8; ++c) a1[c] = fmaxf(z1[c]*sc1[c] + sh1[c], 0.f);
        float z2[16]; lin<16,8>(a1, W2, b2, z2);
#pragma unroll
        for (int o = 0; o < 16; ++o) { acc[o] += z2[o]; acc[16+o] += z2[o]*z2[o]; }
    }
    block_reduce_atomic<32>(acc, pstats + (blockIdx.x & 7) * PSTRIDE + 32);
}

// ---------------------------------------------------------------------------
// k_fin: sum partials (agent-scope loads) -> fold coefficients (1 block)
// fold: [0..7]=sc0 [8..15]=sh0 [16..79]=W1f [80..87]=b1f [88..215]=W2f [216..231]=b2f
// ---------------------------------------------------------------------------
__global__ void k_fin(const float* __restrict__ pstats,
                      const float* __restrict__ g0, const float* __restrict__ be0,
                      const float* __restrict__ W1, const float* __restrict__ b1,
                      const float* __restrict__ g1, const float* __restrict__ be1,
                      const float* __restrict__ W2, const float* __restrict__ b2,
                      const float* __restrict__ g2, const float* __restrict__ be2,
                      float* __restrict__ fold) {
    __shared__ float S[64];
    __shared__ float sc[32], sh[32];
    const int t = threadIdx.x;
    const float invM = 1.0f / (float)MTOT;
    if (t < 64) {
        float s = 0.f;
#pragma unroll
        for (int p = 0; p < 8; ++p) s += ld_dev(pstats + p*PSTRIDE + t);
        S[t] = s;
    }
    __syncthreads();
    if (t < 8) {
        const float m = S[t]*invM, v = S[8+t]*invM - m*m;
        const float s = frsq(v + 1e-5f) * g0[t];
        sc[t] = s; sh[t] = be0[t] - m*s;
    } else if (t < 16) {
        const int c = t - 8;
        const float m = S[16+c]*invM, v = S[24+c]*invM - m*m;
        const float s = frsq(v + 1e-5f) * g1[c];
        sc[t] = s; sh[t] = be1[c] - m*s;
    } else if (t < 32) {
        const int c = t - 16;
        const float m = S[32+c]*invM, v = S[48+c]*invM - m*m;
        const float s = frsq(v + 1e-5f) * g2[c];
        sc[t] = s; sh[t] = be2[c] - m*s;
    }
    __syncthreads();
    if (t < 8)   { fold[t] = sc[t]; fold[8+t] = sh[t]; }
    if (t < 64)  fold[16 + t] = sc[8 + (t >> 3)] * W1[t];
    if (t < 8)   fold[80 + t] = sc[8 + t]*b1[t] + sh[8 + t];
    if (t < 128) fold[88 + t] = sc[16 + (t >> 3)] * W2[t];
    if (t < 16)  fold[216 + t] = sc[16 + t]*b2[t] + sh[16 + t];
}

// ---------------------------------------------------------------------------
// k_fused: R8/R14 verbatim (prefetch prologue + fold-P0 + MFMA P1-P4)
// LDS: h1buf [256][40bf16] @0 (20480) -> overlaid by aggL [16][520bf16]
//      h2T [32][264bf16] @20480 (16896);  wBT [16p][272bf16] @37376 (8704)
// ---------------------------------------------------------------------------
__global__ __launch_bounds__(256, 3)
void k_fused(const float* __restrict__ feats,
             const unsigned short* __restrict__ featsbf,
             const int* __restrict__ nei,
             const float* __restrict__ bm1, const float* __restrict__ bm2,
             const float* __restrict__ blin, const float* __restrict__ fold,
             const short* __restrict__ fWm1, const short* __restrict__ fWm2,
             const short* __restrict__ fWlin,
             const unsigned short* __restrict__ z0ws,
             const unsigned short* __restrict__ rmws,
             float* __restrict__ out) {
    __shared__ __align__(16) unsigned char smem[46080];
    const int t    = threadIdx.x;
    const int lane = t & 63;
    const int wv   = t >> 6;
    const int blk  = blockIdx.x;
    const int sbase = blk * 256;
    const int b     = (blk >= 2048) ? 1 : 0;
    const int lrow  = lane & 15;
    const int kq    = lane >> 4;

    // ---- prologue: issue ALL global loads up front ----
    int njv[4];
#pragma unroll
    for (int mt = 0; mt < 4; ++mt)
        njv[mt] = nei[sbase + wv*64 + mt*16 + lrow];

    const uint4 zz = *(const uint4*)(z0ws + (size_t)(sbase + t)*8);

    short8 bW1[3][2];
#pragma unroll
    for (int ks = 0; ks < 3; ++ks)
#pragma unroll
        for (int nt = 0; nt < 2; ++nt)
            bW1[ks][nt] = *(const short8*)(fWm1 + ((ks*2 + nt)*64 + lane)*8);
    short8 bW2[2];
    bW2[0] = *(const short8*)(fWm2 + (0*64 + lane)*8);
    bW2[1] = *(const short8*)(fWm2 + (1*64 + lane)*8);

    short8 fa[4][2];
    uint2  rmv[4];
#pragma unroll
    for (int mt = 0; mt < 4; ++mt) {
        const unsigned short* F = featsbf + ((size_t)(b*NN + njv[mt])) * CC;
        fa[mt][0] = *(const short8*)(F + kq*8);
        fa[mt][1] = *(const short8*)(F + 32 + kq*8);
        rmv[mt]   = *(const uint2*)(rmws + (size_t)(sbase + wv*64 + mt*16 + lrow)*4);
    }

    // ---- P0: z0 -> folded wn chain -> w -> wBT (hides load latency) ----
    {
        const unsigned short* q = (const unsigned short*)&zz;
        float a0[8];
#pragma unroll
        for (int c = 0; c < 8; ++c) a0[c] = fmaxf(bf2f(q[c])*fold[c] + fold[8+c], 0.f);
        float a1[8];
#pragma unroll
        for (int o = 0; o < 8; ++o) {
            float acc = fold[80 + o];
#pragma unroll
            for (int c = 0; c < 8; ++c) acc += a0[c] * fold[16 + o*8 + c];
            a1[o] = fmaxf(acc, 0.f);
        }
        const int p = t >> 4, kk = t & 15;
        unsigned short* WBT = (unsigned short*)(smem + 37376);
#pragma unroll
        for (int o = 0; o < 16; ++o) {
            float acc = fold[216 + o];
#pragma unroll
            for (int c = 0; c < 8; ++c) acc += a1[c] * fold[88 + o*8 + c];
            WBT[p*272 + o*16 + kk] = (unsigned short)f2bf(fmaxf(acc, 0.f));
        }
    }

    // ---- P1: h1 = relu([gfeat,rmiu] @ Wm1^T + bm1) ----
    {
        f32x4 C1[4][2];
#pragma unroll
        for (int mt = 0; mt < 4; ++mt)
#pragma unroll
            for (int nt = 0; nt < 2; ++nt)
                C1[mt][nt] = (f32x4){0.f, 0.f, 0.f, 0.f};

#pragma unroll
        for (int mt = 0; mt < 4; ++mt) {
            C1[mt][0] = mfma16(fa[mt][0], bW1[0][0], C1[mt][0]);
            C1[mt][1] = mfma16(fa[mt][0], bW1[0][1], C1[mt][1]);
            C1[mt][0] = mfma16(fa[mt][1], bW1[1][0], C1[mt][0]);
            C1[mt][1] = mfma16(fa[mt][1], bW1[1][1], C1[mt][1]);
            short8 ar = (short8){0,0,0,0,0,0,0,0};
            if (kq == 0)
                *(uint2*)&ar = rmv[mt];
            C1[mt][0] = mfma16(ar, bW1[2][0], C1[mt][0]);
            C1[mt][1] = mfma16(ar, bW1[2][1], C1[mt][1]);
        }
        unsigned short* H1 = (unsigned short*)smem;
#pragma unroll
        for (int mt = 0; mt < 4; ++mt)
#pragma unroll
            for (int nt = 0; nt < 2; ++nt) {
                const int c = nt*16 + lrow;
                const float bias = bm1[c];
#pragma unroll
                for (int reg = 0; reg < 4; ++reg) {
                    const int s = wv*64 + mt*16 + kq*4 + reg;
                    H1[s*40 + c] = (unsigned short)f2bf(fmaxf(C1[mt][nt][reg] + bias, 0.f));
                }
            }
    }

    // ---- P2: h2 = relu(h1 @ fWm2 + bm2) -> h2T ----
    {
        const unsigned short* H1 = (const unsigned short*)smem;
        f32x4 C2[4][2];
#pragma unroll
        for (int mt = 0; mt < 4; ++mt)
#pragma unroll
            for (int nt = 0; nt < 2; ++nt)
                C2[mt][nt] = (f32x4){0.f, 0.f, 0.f, 0.f};
#pragma unroll
        for (int mt = 0; mt < 4; ++mt) {
            const int s = wv*64 + mt*16 + lrow;
            const short8 a = *(const short8*)(H1 + s*40 + kq*8);
            C2[mt][0] = mfma16(a, bW2[0], C2[mt][0]);
            C2[mt][1] = mfma16(a, bW2[1], C2[mt][1]);
        }
        unsigned short* H2T = (unsigned short*)(smem + 20480);
#pragma unroll
        for (int mt = 0; mt < 4; ++mt)
#pragma unroll
            for (int nt = 0; nt < 2; ++nt) {
                const int c = nt*16 + lrow;
                const float bias = bm2[c];
                const int s0 = wv*64 + mt*16 + kq*4;
                const float r0 = fmaxf(C2[mt][nt][0] + bias, 0.f);
                const float r1 = fmaxf(C2[mt][nt][1] + bias, 0.f);
                const float r2 = fmaxf(C2[mt][nt][2] + bias, 0.f);
                const float r3 = fmaxf(C2[mt][nt][3] + bias, 0.f);
                uint2 pk; pk.x = cvtpk(r0, r1); pk.y = cvtpk(r2, r3);
                *(uint2*)&H2T[c*264 + s0] = pk;
            }
    }

    __syncthreads();   // h1buf reads done before aggL overlays region 0

    // ---- P3: agg[p] = h2_p^T @ w_p -> aggL [p][c*16+j] bf16 ----
    {
        const unsigned short* H2T = (const unsigned short*)(smem + 20480);
        const unsigned short* WBT = (const unsigned short*)(smem + 37376);
        unsigned short* AGG = (unsigned short*)smem;
#pragma unroll
        for (int pi = 0; pi < 4; ++pi) {
            const int p = wv*4 + pi;
            short8 bf = (short8){0,0,0,0,0,0,0,0};
            if (kq < 2)
                bf = *(const short8*)(WBT + p*272 + lrow*16 + kq*8);
#pragma unroll
            for (int ct = 0; ct < 2; ++ct) {
                short8 af = (short8){0,0,0,0,0,0,0,0};
                if (kq < 2) {
                    const int c = ct*16 + lrow;
                    af = *(const short8*)(H2T + c*264 + p*16 + kq*8);
                }
                f32x4 Cg = (f32x4){0.f, 0.f, 0.f, 0.f};
                Cg = mfma16(af, bf, Cg);
#pragma unroll
                for (int reg = 0; reg < 4; ++reg) {
                    const int c = ct*16 + kq*4 + reg;
                    AGG[p*520 + c*16 + lrow] = (unsigned short)f2bf(Cg[reg]);
                }
            }
        }
    }

    __syncthreads();   // aggL complete

    // ---- P4: out = relu(agg @ Wlin^T + blin) + feats ----
    {
        const unsigned short* AGG = (const unsigned short*)smem;
        const int nt = wv;
        f32x4 Co = (f32x4){0.f, 0.f, 0.f, 0.f};
#pragma unroll
        for (int ks = 0; ks < 16; ++ks) {
            const short8 a  = *(const short8*)(AGG + lrow*520 + ks*32 + kq*8);
            const short8 bf = *(const short8*)(fWlin + ((ks*4 + nt)*64 + lane)*8);
            Co = mfma16(a, bf, Co);
        }
        const int o = nt*16 + lrow;
        const float bias = blin[o];
#pragma unroll
        for (int reg = 0; reg < 4; ++reg) {
            const int p = kq*4 + reg;
            const size_t gp = (size_t)blk*16 + p;
            out[gp*CC + o] = fmaxf(Co[reg] + bias, 0.f) + feats[gp*CC + o];
        }
    }
}

// ---------------------------------------------------------------------------
extern "C" void kernel_launch(void* const* d_in, const int* in_sizes, int n_in,
                              void* d_out, int out_size, void* d_ws, size_t ws_size,
                              hipStream_t stream) {
    const float* xyz  = (const float*)d_in[0];
    const float* feats= (const float*)d_in[1];
    const float* xyzn = (const float*)d_in[2];
    const int*   nei  = (const int*)  d_in[3];
    const float* Wm1  = (const float*)d_in[4];
    const float* bm1  = (const float*)d_in[5];
    const float* Wm2  = (const float*)d_in[6];
    const float* bm2  = (const float*)d_in[7];
    const float* W0   = (const float*)d_in[8];
    const float* b0   = (const float*)d_in[9];
    const float* g0   = (const float*)d_in[10];
    const float* be0  = (const float*)d_in[11];
    const float* W1   = (const float*)d_in[12];
    const float* b1   = (const float*)d_in[13];
    const float* g1   = (const float*)d_in[14];
    const float* be1  = (const float*)d_in[15];
    const float* W2   = (const float*)d_in[16];
    const float* b2   = (const float*)d_in[17];
    const float* g2   = (const float*)d_in[18];
    const float* be2  = (const float*)d_in[19];
    const float* Wlin = (const float*)d_in[20];
    const float* blin = (const float*)d_in[21];

    float* out = (float*)d_out;
    char*  ws  = (char*)d_ws;

    float*          pstats  = (float*)ws;                        // 8x64 f = 2 KB
    float*          fold    = (float*)(ws + 8192);               // 232 f
    short*          fWm1    = (short*)(ws + 10240);              // 6144 B
    short*          fWm2    = (short*)(ws + 16384);              // 2048 B
    short*          fWlin   = (short*)(ws + 20480);              // 64 KB
    unsigned short* featsbf = (unsigned short*)(ws + 131072);    // 8 MB
    unsigned short* z0ws    = (unsigned short*)(ws + 8519680);   // 16 MB
    unsigned short* rmws    = (unsigned short*)(ws + 25296896);  // 8 MB

    hipMemsetAsync(pstats, 0, 8192, stream);

    kA<<<1024, 256, 0, stream>>>(xyz, xyzn, nei, W0, b0, Wm1, Wm2, Wlin,
                                 feats, z0ws, rmws, fWm1, fWm2, fWlin,
                                 featsbf, pstats);
    kB<<<1024, 256, 0, stream>>>(z0ws, W1, b1, g0, be0, pstats);
    kC<<<1024, 256, 0, stream>>>(z0ws, W1, b1, W2, b2, g0, be0, g1, be1,
                                 pstats);
    k_fin<<<1, 256, 0, stream>>>(pstats, g0, be0, W1, b1, g1, be1,
                                 W2, b2, g2, be2, fold);
    k_fused<<<4096, 256, 0, stream>>>(feats, featsbf, nei, bm1, bm2, blin,
                                      fold, fWm1, fWm2, fWlin, z0ws, rmws, out);
}

// Round 19
// 102.978 us; speedup vs baseline: 1.8962x; 1.2234x over previous
//
#include <hip/hip_runtime.h>
#include <math.h>

#define BB 2
#define NN 32768
#define KK 16
#define CC 64
#define MTOT (BB*NN*KK)   // 1048576

typedef short short8 __attribute__((ext_vector_type(8)));
typedef float f32x4 __attribute__((ext_vector_type(4)));

static_assert(MTOT == 1048576, "size");

__device__ __forceinline__ float frsq(float x) { return __builtin_amdgcn_rsqf(x); }

__device__ __forceinline__ unsigned cvtpk(float lo, float hi) {
    unsigned r;
    asm("v_cvt_pk_bf16_f32 %0, %1, %2" : "=v"(r) : "v"(lo), "v"(hi));
    return r;
}

__device__ __forceinline__ short f2bf(float f) {
    union { float f; unsigned u; } c; c.f = f;
    const unsigned r = c.u + 0x7FFFu + ((c.u >> 16) & 1u);   // RNE
    return (short)(r >> 16);
}

__device__ __forceinline__ float bf2f(unsigned short u) {
    union { unsigned u; float f; } c; c.u = ((unsigned)u) << 16; return c.f;
}

// agent-scope load: guards against stale per-XCD L2/L1 for cross-dispatch RAW
// (read-side hardening only — NO producer threadfence: a device-scope fence in
// kA would drain ~32 MB of pending ws writes per block and cost ~75 µs, R17.)
__device__ __forceinline__ float ld_dev(const float* p) {
    return __hip_atomic_load(p, __ATOMIC_RELAXED, __HIP_MEMORY_SCOPE_AGENT);
}

__device__ __forceinline__ f32x4 mfma16(short8 a, short8 b, f32x4 c) {
    return __builtin_amdgcn_mfma_f32_16x16x32_bf16(a, b, c, 0, 0, 0);
}

// pstats layout: 8 copies x 64 floats (copy p at pstats + p*64), j-semantics:
//   j 0..15  = stats0 (sum, sumsq)   j 16..31 = stats1   j 32..63 = stats2
#define PSTRIDE 64

// block-cooperative partial sum: threads t<NJ each sum one j-column with
// agent-scope loads into LDS; all threads then read the LDS copy.
// (R18 did 256 redundant ld_dev sweeps per block -> ~16 us total; this is 1.)
template<int NJ>
__device__ __forceinline__ void sum_partials_blk(const float* __restrict__ pst,
                                                 float* SS /*LDS[NJ]*/) {
    const int t = threadIdx.x;
    if (t < NJ) {
        float s = 0.f;
#pragma unroll
        for (int p = 0; p < 8; ++p) s += ld_dev(pst + p*PSTRIDE + t);
        SS[t] = s;
    }
    __syncthreads();
}

// ---------------------------------------------------------------------------
// geometry with preloaded center (cx..nmz) and neighbor index nj
// ---------------------------------------------------------------------------
__device__ __forceinline__ void geom12c(int b, int nj,
                                        float cx, float cy, float cz,
                                        float nmx, float nmy, float nmz,
                                        const float* __restrict__ xyz,
                                        const float* __restrict__ xyzn,
                                        float* win) {
    const size_t gj = (size_t)(b * NN + nj);
    const float gx = xyz[gj*3],  gy = xyz[gj*3+1],  gz = xyz[gj*3+2];
    const float gnx = xyzn[gj*3], gny = xyzn[gj*3+1], gnz = xyzn[gj*3+2];

    const float rx = gx - cx, ry = gy - cy, rz = gz - cz;
    const float ss = rx*rx + ry*ry + rz*rz;
    const float rinv = frsq(fmaxf(ss, 1e-24f));
    const float rlen = ss * rinv;
    const float rhx = rx*rinv, rhy = ry*rinv, rhz = rz*rinv;

    const float d_nr = nmx*rhx + nmy*rhy + nmz*rhz;
    float vx = nmx - d_nr*rhx, vy = nmy - d_nr*rhy, vz = nmz - d_nr*rhz;
    const float vinv = frsq(fmaxf(vx*vx + vy*vy + vz*vz, 1e-24f));
    vx *= vinv; vy *= vinv; vz *= vinv;

    float wx = rhy*vz - rhz*vy;
    float wy = rhz*vx - rhx*vz;
    float wz = rhx*vy - rhy*vx;
    const float winv = frsq(fmaxf(wx*wx + wy*wy + wz*wz, 1e-24f));
    wx *= winv; wy *= winv; wz *= winv;

    const float th1 = gnx*nmx + gny*nmy + gnz*nmz;
    const float th3 = rhx*gnx + rhy*gny + rhz*gnz;
    const float th4 = rx*nmx + ry*nmy + rz*nmz;
    const float th6 = gnx*vx + gny*vy + gnz*vz;
    const float th7 = gnx*wx + gny*wy + gnz*wz;
    const float ccx = gny*nmz - gnz*nmy;
    const float ccy = gnz*nmx - gnx*nmz;
    const float ccz = gnx*nmy - gny*nmx;
    const float th8 = rx*ccx + ry*ccy + rz*ccz;

    win[0]=th1; win[1]=d_nr; win[2]=th3; win[3]=th4; win[4]=th3; win[5]=th6;
    win[6]=th7; win[7]=th8; win[8]=rlen; win[9]=rx; win[10]=ry; win[11]=rz;
}

template<int ON, int IN>
__device__ __forceinline__ void lin(const float* a, const float* __restrict__ W,
                                    const float* __restrict__ bias, float* z) {
#pragma unroll
    for (int o = 0; o < ON; ++o) {
        float acc = bias[o];
#pragma unroll
        for (int c = 0; c < IN; ++c) acc += a[c] * W[o*IN + c];
        z[o] = acc;
    }
}

template<int NV>
__device__ __forceinline__ void block_reduce_atomic(const float* v, float* gdst) {
    __shared__ float red[NV * 4];
    const int lane = threadIdx.x & 63;
    const int wv   = threadIdx.x >> 6;
    float tmp[NV];
#pragma unroll
    for (int i = 0; i < NV; ++i) {
        float x = v[i];
#pragma unroll
        for (int off = 32; off > 0; off >>= 1) x += __shfl_down(x, off, 64);
        tmp[i] = x;
    }
    if (lane == 0) {
#pragma unroll
        for (int i = 0; i < NV; ++i) red[wv * NV + i] = tmp[i];
    }
    __syncthreads();
    if (threadIdx.x < NV) {
        float s = red[threadIdx.x] + red[NV + threadIdx.x] +
                  red[2*NV + threadIdx.x] + red[3*NV + threadIdx.x];
        atomicAdd(gdst + threadIdx.x, s);
    }
}

// ---------------------------------------------------------------------------
// kA: prep (weight frags + featsbf) + geometry -> z0 bf16 + rm4 + stats0
// Each thread: 4 CONSECUTIVE samples (share one center point; int4 nei load).
// ---------------------------------------------------------------------------
__global__ __launch_bounds__(256)
void kA(const float* __restrict__ xyz, const float* __restrict__ xyzn,
        const int* __restrict__ nei, const float* __restrict__ W0,
        const float* __restrict__ b0,
        const float* __restrict__ Wm1, const float* __restrict__ Wm2,
        const float* __restrict__ Wlin, const float* __restrict__ feats,
        unsigned short* __restrict__ z0ws, unsigned short* __restrict__ rmws,
        short* __restrict__ fWm1, short* __restrict__ fWm2,
        short* __restrict__ fWlin, unsigned short* __restrict__ featsbf,
        float* __restrict__ pstats) {
    const int t = threadIdx.x;
    const int gid  = blockIdx.x * 256 + t;
    const int gstr = gridDim.x * 256;

    for (int i = gid; i < 3072; i += gstr) {          // Wm1^T [96pad x 32]
        const int j = i & 7, l = (i >> 3) & 63, fn = i >> 9;
        const int ks = fn >> 1, nt = fn & 1;
        const int k = ks*32 + ((l >> 4) * 8) + j, n = nt*16 + (l & 15);
        fWm1[i] = (k < 67) ? f2bf(Wm1[n*67 + k]) : (short)0;
    }
    for (int i = gid; i < 1024; i += gstr) {          // Wm2^T [32 x 32]
        const int j = i & 7, l = (i >> 3) & 63, nt = i >> 9;
        const int k = ((l >> 4) * 8) + j, n = nt*16 + (l & 15);
        fWm2[i] = f2bf(Wm2[n*32 + k]);
    }
    for (int i = gid; i < 32768; i += gstr) {         // Wlin^T [512 x 64]
        const int j = i & 7, l = (i >> 3) & 63, fn = i >> 9;
        const int ks = fn >> 2, nt = fn & 3;
        const int k = ks*32 + ((l >> 4) * 8) + j, n = nt*16 + (l & 15);
        fWlin[i] = f2bf(Wlin[n*512 + k]);
    }
    for (int i = gid; i < (BB*NN*CC)/4; i += gstr) {  // feats -> bf16
        const float4 f = *(const float4*)(feats + (size_t)i*4);
        uint2 p; p.x = cvtpk(f.x, f.y); p.y = cvtpk(f.z, f.w);
        *(uint2*)(featsbf + (size_t)i*4) = p;
    }

    // ---- geometry: 4 consecutive samples, shared center ----
    const int s0 = gid * 4;
    const int pn = s0 >> 4;
    const int b  = pn >> 15;
    const int4 nj4 = *(const int4*)(nei + s0);
    const float cx  = xyz [(size_t)pn*3], cy  = xyz [(size_t)pn*3+1], cz  = xyz [(size_t)pn*3+2];
    const float nmx = xyzn[(size_t)pn*3], nmy = xyzn[(size_t)pn*3+1], nmz = xyzn[(size_t)pn*3+2];
    const int njs[4] = {nj4.x, nj4.y, nj4.z, nj4.w};

    float acc[16];
#pragma unroll
    for (int i = 0; i < 16; ++i) acc[i] = 0.f;
#pragma unroll
    for (int i = 0; i < 4; ++i) {
        const int s = s0 + i;
        float win[12];
        geom12c(b, njs[i], cx, cy, cz, nmx, nmy, nmz, xyz, xyzn, win);
        float z0[8];  lin<8,12>(win, W0, b0, z0);
        uint4 zp;
        zp.x = cvtpk(z0[0], z0[1]); zp.y = cvtpk(z0[2], z0[3]);
        zp.z = cvtpk(z0[4], z0[5]); zp.w = cvtpk(z0[6], z0[7]);
        *(uint4*)(z0ws + (size_t)s*8) = zp;
        uint2 rp; rp.x = cvtpk(win[9], win[10]); rp.y = cvtpk(win[11], 0.0f);
        *(uint2*)(rmws + (size_t)s*4) = rp;
#pragma unroll
        for (int o = 0; o < 8; ++o) { acc[o] += z0[o]; acc[8+o] += z0[o]*z0[o]; }
    }
    block_reduce_atomic<16>(acc, pstats + (blockIdx.x & 7) * PSTRIDE);
}

// ---------------------------------------------------------------------------
// kB: z0 -> a0 (BN coefs from LDS-summed partials) -> z1; stats1
// ---------------------------------------------------------------------------
__global__ __launch_bounds__(256)
void kB(const unsigned short* __restrict__ z0ws, const float* __restrict__ W1,
        const float* __restrict__ b1, const float* __restrict__ g0,
        const float* __restrict__ be0, float* __restrict__ pstats) {
    __shared__ float SS[16];
    const int t = threadIdx.x;
    const float invM = 1.0f / (float)MTOT;
    sum_partials_blk<16>(pstats, SS);
    float sc0[8], sh0[8];
#pragma unroll
    for (int c = 0; c < 8; ++c) {
        const float m = SS[c] * invM;
        const float v = SS[8 + c] * invM - m*m;
        const float s = frsq(v + 1e-5f) * g0[c];
        sc0[c] = s; sh0[c] = be0[c] - m*s;
    }
    float acc[16];
#pragma unroll
    for (int i = 0; i < 16; ++i) acc[i] = 0.f;
#pragma unroll
    for (int i = 0; i < 4; ++i) {
        const int s = blockIdx.x*1024 + i*256 + t;
        const uint4 zz = *(const uint4*)(z0ws + (size_t)s*8);
        const unsigned short* q = (const unsigned short*)&zz;
        float a0[8];
#pragma unroll
        for (int c = 0; c < 8; ++c) a0[c] = fmaxf(bf2f(q[c])*sc0[c] + sh0[c], 0.f);
        float z1[8]; lin<8,8>(a0, W1, b1, z1);
#pragma unroll
        for (int o = 0; o < 8; ++o) { acc[o] += z1[o]; acc[8+o] += z1[o]*z1[o]; }
    }
    block_reduce_atomic<16>(acc, pstats + (blockIdx.x & 7) * PSTRIDE + 16);
}

// ---------------------------------------------------------------------------
// kC: z0 -> a0 -> z1 -> a1 -> z2; stats2 (coefs from LDS-summed partials)
// ---------------------------------------------------------------------------
__global__ __launch_bounds__(256)
void kC(const unsigned short* __restrict__ z0ws, const float* __restrict__ W1,
        const float* __restrict__ b1, const float* __restrict__ W2,
        const float* __restrict__ b2, const float* __restrict__ g0,
        const float* __restrict__ be0, const float* __restrict__ g1,
        const float* __restrict__ be1, float* __restrict__ pstats) {
    __shared__ float SS[32];
    const int t = threadIdx.x;
    const float invM = 1.0f / (float)MTOT;
    sum_partials_blk<32>(pstats, SS);
    float sc0[8], sh0[8], sc1[8], sh1[8];
#pragma unroll
    for (int c = 0; c < 8; ++c) {
        float m = SS[c] * invM;
        float v = SS[8 + c] * invM - m*m;
        float s = frsq(v + 1e-5f) * g0[c];
        sc0[c] = s; sh0[c] = be0[c] - m*s;
        m = SS[16 + c] * invM;
        v = SS[24 + c] * invM - m*m;
        s = frsq(v + 1e-5f) * g1[c];
        sc1[c] = s; sh1[c] = be1[c] - m*s;
    }
    float acc[32];
#pragma unroll
    for (int i = 0; i < 32; ++i) acc[i] = 0.f;
#pragma unroll
    for (int i = 0; i < 4; ++i) {
        const int s = blockIdx.x*1024 + i*256 + t;
        const uint4 zz = *(const uint4*)(z0ws + (size_t)s*8);
        const unsigned short* q = (const unsigned short*)&zz;
        float a0[8];
#pragma unroll
        for (int c = 0; c < 8; ++c) a0[c] = fmaxf(bf2f(q[c])*sc0[c] + sh0[c], 0.f);
        float z1[8]; lin<8,8>(a0, W1, b1, z1);
        float a1[8];
#pragma unroll
        for (int c = 0; c < 8; ++c) a1[c] = fmaxf(z1[c]*sc1[c] + sh1[c], 0.f);
        float z2[16]; lin<16,8>(a1, W2, b2, z2);
#pragma unroll
        for (int o = 0; o < 16; ++o) { acc[o] += z2[o]; acc[16+o] += z2[o]*z2[o]; }
    }
    block_reduce_atomic<32>(acc, pstats + (blockIdx.x & 7) * PSTRIDE + 32);
}

// ---------------------------------------------------------------------------
// k_fin: sum partials (agent-scope loads) -> fold coefficients (1 block)
// fold: [0..7]=sc0 [8..15]=sh0 [16..79]=W1f [80..87]=b1f [88..215]=W2f [216..231]=b2f
// ---------------------------------------------------------------------------
__global__ void k_fin(const float* __restrict__ pstats,
                      const float* __restrict__ g0, const float* __restrict__ be0,
                      const float* __restrict__ W1, const float* __restrict__ b1,
                      const float* __restrict__ g1, const float* __restrict__ be1,
                      const float* __restrict__ W2, const float* __restrict__ b2,
                      const float* __restrict__ g2, const float* __restrict__ be2,
                      float* __restrict__ fold) {
    __shared__ float S[64];
    __shared__ float sc[32], sh[32];
    const int t = threadIdx.x;
    const float invM = 1.0f / (float)MTOT;
    if (t < 64) {
        float s = 0.f;
#pragma unroll
        for (int p = 0; p < 8; ++p) s += ld_dev(pstats + p*PSTRIDE + t);
        S[t] = s;
    }
    __syncthreads();
    if (t < 8) {
        const float m = S[t]*invM, v = S[8+t]*invM - m*m;
        const float s = frsq(v + 1e-5f) * g0[t];
        sc[t] = s; sh[t] = be0[t] - m*s;
    } else if (t < 16) {
        const int c = t - 8;
        const float m = S[16+c]*invM, v = S[24+c]*invM - m*m;
        const float s = frsq(v + 1e-5f) * g1[c];
        sc[t] = s; sh[t] = be1[c] - m*s;
    } else if (t < 32) {
        const int c = t - 16;
        const float m = S[32+c]*invM, v = S[48+c]*invM - m*m;
        const float s = frsq(v + 1e-5f) * g2[c];
        sc[t] = s; sh[t] = be2[c] - m*s;
    }
    __syncthreads();
    if (t < 8)   { fold[t] = sc[t]; fold[8+t] = sh[t]; }
    if (t < 64)  fold[16 + t] = sc[8 + (t >> 3)] * W1[t];
    if (t < 8)   fold[80 + t] = sc[8 + t]*b1[t] + sh[8 + t];
    if (t < 128) fold[88 + t] = sc[16 + (t >> 3)] * W2[t];
    if (t < 16)  fold[216 + t] = sc[16 + t]*b2[t] + sh[16 + t];
}

// ---------------------------------------------------------------------------
// k_fused: R8/R14 verbatim (prefetch prologue + fold-P0 + MFMA P1-P4)
// LDS: h1buf [256][40bf16] @0 (20480) -> overlaid by aggL [16][520bf16]
//      h2T [32][264bf16] @20480 (16896);  wBT [16p][272bf16] @37376 (8704)
// ---------------------------------------------------------------------------
__global__ __launch_bounds__(256, 3)
void k_fused(const float* __restrict__ feats,
             const unsigned short* __restrict__ featsbf,
             const int* __restrict__ nei,
             const float* __restrict__ bm1, const float* __restrict__ bm2,
             const float* __restrict__ blin, const float* __restrict__ fold,
             const short* __restrict__ fWm1, const short* __restrict__ fWm2,
             const short* __restrict__ fWlin,
             const unsigned short* __restrict__ z0ws,
             const unsigned short* __restrict__ rmws,
             float* __restrict__ out) {
    __shared__ __align__(16) unsigned char smem[46080];
    const int t    = threadIdx.x;
    const int lane = t & 63;
    const int wv   = t >> 6;
    const int blk  = blockIdx.x;
    const int sbase = blk * 256;
    const int b     = (blk >= 2048) ? 1 : 0;
    const int lrow  = lane & 15;
    const int kq    = lane >> 4;

    // ---- prologue: issue ALL global loads up front ----
    int njv[4];
#pragma unroll
    for (int mt = 0; mt < 4; ++mt)
        njv[mt] = nei[sbase + wv*64 + mt*16 + lrow];

    const uint4 zz = *(const uint4*)(z0ws + (size_t)(sbase + t)*8);

    short8 bW1[3][2];
#pragma unroll
    for (int ks = 0; ks < 3; ++ks)
#pragma unroll
        for (int nt = 0; nt < 2; ++nt)
            bW1[ks][nt] = *(const short8*)(fWm1 + ((ks*2 + nt)*64 + lane)*8);
    short8 bW2[2];
    bW2[0] = *(const short8*)(fWm2 + (0*64 + lane)*8);
    bW2[1] = *(const short8*)(fWm2 + (1*64 + lane)*8);

    short8 fa[4][2];
    uint2  rmv[4];
#pragma unroll
    for (int mt = 0; mt < 4; ++mt) {
        const unsigned short* F = featsbf + ((size_t)(b*NN + njv[mt])) * CC;
        fa[mt][0] = *(const short8*)(F + kq*8);
        fa[mt][1] = *(const short8*)(F + 32 + kq*8);
        rmv[mt]   = *(const uint2*)(rmws + (size_t)(sbase + wv*64 + mt*16 + lrow)*4);
    }

    // ---- P0: z0 -> folded wn chain -> w -> wBT (hides load latency) ----
    {
        const unsigned short* q = (const unsigned short*)&zz;
        float a0[8];
#pragma unroll
        for (int c = 0; c < 8; ++c) a0[c] = fmaxf(bf2f(q[c])*fold[c] + fold[8+c], 0.f);
        float a1[8];
#pragma unroll
        for (int o = 0; o < 8; ++o) {
            float acc = fold[80 + o];
#pragma unroll
            for (int c = 0; c < 8; ++c) acc += a0[c] * fold[16 + o*8 + c];
            a1[o] = fmaxf(acc, 0.f);
        }
        const int p = t >> 4, kk = t & 15;
        unsigned short* WBT = (unsigned short*)(smem + 37376);
#pragma unroll
        for (int o = 0; o < 16; ++o) {
            float acc = fold[216 + o];
#pragma unroll
            for (int c = 0; c < 8; ++c) acc += a1[c] * fold[88 + o*8 + c];
            WBT[p*272 + o*16 + kk] = (unsigned short)f2bf(fmaxf(acc, 0.f));
        }
    }

    // ---- P1: h1 = relu([gfeat,rmiu] @ Wm1^T + bm1) ----
    {
        f32x4 C1[4][2];
#pragma unroll
        for (int mt = 0; mt < 4; ++mt)
#pragma unroll
            for (int nt = 0; nt < 2; ++nt)
                C1[mt][nt] = (f32x4){0.f, 0.f, 0.f, 0.f};

#pragma unroll
        for (int mt = 0; mt < 4; ++mt) {
            C1[mt][0] = mfma16(fa[mt][0], bW1[0][0], C1[mt][0]);
            C1[mt][1] = mfma16(fa[mt][0], bW1[0][1], C1[mt][1]);
            C1[mt][0] = mfma16(fa[mt][1], bW1[1][0], C1[mt][0]);
            C1[mt][1] = mfma16(fa[mt][1], bW1[1][1], C1[mt][1]);
            short8 ar = (short8){0,0,0,0,0,0,0,0};
            if (kq == 0)
                *(uint2*)&ar = rmv[mt];
            C1[mt][0] = mfma16(ar, bW1[2][0], C1[mt][0]);
            C1[mt][1] = mfma16(ar, bW1[2][1], C1[mt][1]);
        }
        unsigned short* H1 = (unsigned short*)smem;
#pragma unroll
        for (int mt = 0; mt < 4; ++mt)
#pragma unroll
            for (int nt = 0; nt < 2; ++nt) {
                const int c = nt*16 + lrow;
                const float bias = bm1[c];
#pragma unroll
                for (int reg = 0; reg < 4; ++reg) {
                    const int s = wv*64 + mt*16 + kq*4 + reg;
                    H1[s*40 + c] = (unsigned short)f2bf(fmaxf(C1[mt][nt][reg] + bias, 0.f));
                }
            }
    }

    // ---- P2: h2 = relu(h1 @ fWm2 + bm2) -> h2T ----
    {
        const unsigned short* H1 = (const unsigned short*)smem;
        f32x4 C2[4][2];
#pragma unroll
        for (int mt = 0; mt < 4; ++mt)
#pragma unroll
            for (int nt = 0; nt < 2; ++nt)
                C2[mt][nt] = (f32x4){0.f, 0.f, 0.f, 0.f};
#pragma unroll
        for (int mt = 0; mt < 4; ++mt) {
            const int s = wv*64 + mt*16 + lrow;
            const short8 a = *(const short8*)(H1 + s*40 + kq*8);
            C2[mt][0] = mfma16(a, bW2[0], C2[mt][0]);
            C2[mt][1] = mfma16(a, bW2[1], C2[mt][1]);
        }
        unsigned short* H2T = (unsigned short*)(smem + 20480);
#pragma unroll
        for (int mt = 0; mt < 4; ++mt)
#pragma unroll
            for (int nt = 0; nt < 2; ++nt) {
                const int c = nt*16 + lrow;
                const float bias = bm2[c];
                const int s0 = wv*64 + mt*16 + kq*4;
                const float r0 = fmaxf(C2[mt][nt][0] + bias, 0.f);
                const float r1 = fmaxf(C2[mt][nt][1] + bias, 0.f);
                const float r2 = fmaxf(C2[mt][nt][2] + bias, 0.f);
                const float r3 = fmaxf(C2[mt][nt][3] + bias, 0.f);
                uint2 pk; pk.x = cvtpk(r0, r1); pk.y = cvtpk(r2, r3);
                *(uint2*)&H2T[c*264 + s0] = pk;
            }
    }

    __syncthreads();   // h1buf reads done before aggL overlays region 0

    // ---- P3: agg[p] = h2_p^T @ w_p -> aggL [p][c*16+j] bf16 ----
    {
        const unsigned short* H2T = (const unsigned short*)(smem + 20480);
        const unsigned short* WBT = (const unsigned short*)(smem + 37376);
        unsigned short* AGG = (unsigned short*)smem;
#pragma unroll
        for (int pi = 0; pi < 4; ++pi) {
            const int p = wv*4 + pi;
            short8 bf = (short8){0,0,0,0,0,0,0,0};
            if (kq < 2)
                bf = *(const short8*)(WBT + p*272 + lrow*16 + kq*8);
#pragma unroll
            for (int ct = 0; ct < 2; ++ct) {
                short8 af = (short8){0,0,0,0,0,0,0,0};
                if (kq < 2) {
                    const int c = ct*16 + lrow;
                    af = *(const short8*)(H2T + c*264 + p*16 + kq*8);
                }
                f32x4 Cg = (f32x4){0.f, 0.f, 0.f, 0.f};
                Cg = mfma16(af, bf, Cg);
#pragma unroll
                for (int reg = 0; reg < 4; ++reg) {
                    const int c = ct*16 + kq*4 + reg;
                    AGG[p*520 + c*16 + lrow] = (unsigned short)f2bf(Cg[reg]);
                }
            }
        }
    }

    __syncthreads();   // aggL complete

    // ---- P4: out = relu(agg @ Wlin^T + blin) + feats ----
    {
        const unsigned short* AGG = (const unsigned short*)smem;
        const int nt = wv;
        f32x4 Co = (f32x4){0.f, 0.f, 0.f, 0.f};
#pragma unroll
        for (int ks = 0; ks < 16; ++ks) {
            const short8 a  = *(const short8*)(AGG + lrow*520 + ks*32 + kq*8);
            const short8 bf = *(const short8*)(fWlin + ((ks*4 + nt)*64 + lane)*8);
            Co = mfma16(a, bf, Co);
        }
        const int o = nt*16 + lrow;
        const float bias = blin[o];
#pragma unroll
        for (int reg = 0; reg < 4; ++reg) {
            const int p = kq*4 + reg;
            const size_t gp = (size_t)blk*16 + p;
            out[gp*CC + o] = fmaxf(Co[reg] + bias, 0.f) + feats[gp*CC + o];
        }
    }
}

// ---------------------------------------------------------------------------
extern "C" void kernel_launch(void* const* d_in, const int* in_sizes, int n_in,
                              void* d_out, int out_size, void* d_ws, size_t ws_size,
                              hipStream_t stream) {
    const float* xyz  = (const float*)d_in[0];
    const float* feats= (const float*)d_in[1];
    const float* xyzn = (const float*)d_in[2];
    const int*   nei  = (const int*)  d_in[3];
    const float* Wm1  = (const float*)d_in[4];
    const float* bm1  = (const float*)d_in[5];
    const float* Wm2  = (const float*)d_in[6];
    const float* bm2  = (const float*)d_in[7];
    const float* W0   = (const float*)d_in[8];
    const float* b0   = (const float*)d_in[9];
    const float* g0   = (const float*)d_in[10];
    const float* be0  = (const float*)d_in[11];
    const float* W1   = (const float*)d_in[12];
    const float* b1   = (const float*)d_in[13];
    const float* g1   = (const float*)d_in[14];
    const float* be1  = (const float*)d_in[15];
    const float* W2   = (const float*)d_in[16];
    const float* b2   = (const float*)d_in[17];
    const float* g2   = (const float*)d_in[18];
    const float* be2  = (const float*)d_in[19];
    const float* Wlin = (const float*)d_in[20];
    const float* blin = (const float*)d_in[21];

    float* out = (float*)d_out;
    char*  ws  = (char*)d_ws;

    float*          pstats  = (float*)ws;                        // 8x64 f = 2 KB
    float*          fold    = (float*)(ws + 8192);               // 232 f
    short*          fWm1    = (short*)(ws + 10240);              // 6144 B
    short*          fWm2    = (short*)(ws + 16384);              // 2048 B
    short*          fWlin   = (short*)(ws + 20480);              // 64 KB
    unsigned short* featsbf = (unsigned short*)(ws + 131072);    // 8 MB
    unsigned short* z0ws    = (unsigned short*)(ws + 8519680);   // 16 MB
    unsigned short* rmws    = (unsigned short*)(ws + 25296896);  // 8 MB

    hipMemsetAsync(pstats, 0, 8192, stream);

    kA<<<1024, 256, 0, stream>>>(xyz, xyzn, nei, W0, b0, Wm1, Wm2, Wlin,
                                 feats, z0ws, rmws, fWm1, fWm2, fWlin,
                                 featsbf, pstats);
    kB<<<1024, 256, 0, stream>>>(z0ws, W1, b1, g0, be0, pstats);
    kC<<<1024, 256, 0, stream>>>(z0ws, W1, b1, W2, b2, g0, be0, g1, be1,
                                 pstats);
    k_fin<<<1, 256, 0, stream>>>(pstats, g0, be0, W1, b1, g1, be1,
                                 W2, b2, g2, be2, fold);
    k_fused<<<4096, 256, 0, stream>>>(feats, featsbf, nei, bm1, bm2, blin,
                                      fold, fWm1, fWm2, fWlin, z0ws, rmws, out);
}